// Round 2
// baseline (176.719 us; speedup 1.0000x reference)
//
#include <hip/hip_runtime.h>
#include <math.h>

// ---- DCT constants (fp32) ----
#define A0c 0.35355339059327373f
#define C1c 0.4903926402016152f
#define C2c 0.46193976625564337f
#define C3c 0.41573480615127262f
#define C5c 0.27778511650980114f
#define C6c 0.19134171618254492f
#define C7c 0.09754516100806417f

#define IMG_W 512
#define IMG_HW (512 * 512)

typedef _Float16 half8 __attribute__((ext_vector_type(8)));
typedef float f8v __attribute__((ext_vector_type(8)));

// In-place 8-point DCT-II (rows of D = 0.5*c(u)*cos((2x+1)u*pi/16))
__device__ __forceinline__ void fdct8(float v[8]) {
    float s0 = v[0] + v[7], s1 = v[1] + v[6], s2 = v[2] + v[5], s3 = v[3] + v[4];
    float d0 = v[0] - v[7], d1 = v[1] - v[6], d2 = v[2] - v[5], d3 = v[3] - v[4];
    float e0 = s0 + s3, e1 = s1 + s2, f0 = s0 - s3, f1 = s1 - s2;
    v[0] = A0c * (e0 + e1);
    v[4] = A0c * (e0 - e1);
    v[2] = C2c * f0 + C6c * f1;
    v[6] = C6c * f0 - C2c * f1;
    v[1] = C1c * d0 + C3c * d1 + C5c * d2 + C7c * d3;
    v[3] = C3c * d0 - C7c * d1 - C1c * d2 - C5c * d3;
    v[5] = C5c * d0 - C1c * d1 + C7c * d2 + C3c * d3;
    v[7] = C7c * d0 - C5c * d1 + C3c * d2 - C1c * d3;
}

// In-place 8-point inverse: x[n] = sum_u D[u][n] c[u]
__device__ __forceinline__ void idct8(float v[8]) {
    float g0 = v[0], g1 = v[1], g2 = v[2], g3 = v[3];
    float g4 = v[4], g5 = v[5], g6 = v[6], g7 = v[7];
    float ep = A0c * (g0 + g4), em = A0c * (g0 - g4);
    float t26a = C2c * g2 + C6c * g6;
    float t26b = C6c * g2 - C2c * g6;
    float e0 = ep + t26a;
    float e1 = em + t26b;
    float e2 = em - t26b;
    float e3 = ep - t26a;
    float o0 = C1c * g1 + C3c * g3 + C5c * g5 + C7c * g7;
    float o1 = C3c * g1 - C7c * g3 - C1c * g5 - C5c * g7;
    float o2 = C5c * g1 - C1c * g3 + C7c * g5 + C3c * g7;
    float o3 = C7c * g1 - C5c * g3 + C3c * g5 - C1c * g7;
    v[0] = e0 + o0; v[7] = e0 - o0;
    v[1] = e1 + o1; v[6] = e1 - o1;
    v[2] = e2 + o2; v[5] = e2 - o2;
    v[3] = e3 + o3; v[4] = e3 - o3;
}

// soft quantize-dequantize: d = x/q; sr = d + 0.5*tanh(15*(d - round(d))); return sr*q
__device__ __forceinline__ float softq(float x, float q, float rq) {
    float d = x * rq;
    float rn = rintf(d);           // nearest-even, matches jnp.round
    float t = d - rn;              // in [-0.5, 0.5]
    float z = 15.0f * t;           // 50*TEMP = 15
    float za = fabsf(z);
    float e = __expf(-2.0f * za);  // >= e^-15, no denormal trouble
    float th = (1.0f - e) * __builtin_amdgcn_rcpf(1.0f + e);
    th = copysignf(th, z);
    return (d + 0.5f * th) * q;
}

template <int CH>
__device__ __forceinline__ void quant_block(float X[8][8]) {
    static constexpr float QL[64] = {
        16,11,10,16,24,40,51,61,  12,12,14,19,26,58,60,55,
        14,13,16,24,40,57,69,56,  14,17,22,29,51,87,80,62,
        18,22,37,56,68,109,103,77, 24,35,55,64,81,104,113,92,
        49,64,78,87,103,121,120,101, 72,92,95,98,112,100,103,99};
    static constexpr float QC[64] = {
        17,18,24,47,99,99,99,99,  18,21,26,66,99,99,99,99,
        24,26,56,99,99,99,99,99,  47,66,99,99,99,99,99,99,
        99,99,99,99,99,99,99,99,  99,99,99,99,99,99,99,99,
        99,99,99,99,99,99,99,99,  99,99,99,99,99,99,99,99};
#pragma unroll
    for (int u = 0; u < 8; ++u) {
#pragma unroll
        for (int v = 0; v < 8; ++v) {
            float q = (CH == 0) ? QL[u * 8 + v] : QC[u * 8 + v];
            float rq = (CH == 0) ? (1.0f / QL[u * 8 + v]) : (1.0f / QC[u * 8 + v]);
            X[u][v] = softq(X[u][v], q, rq);
        }
    }
}

__device__ __forceinline__ void transform_block(float X[8][8], int ch) {
    // forward: rows (over y), then columns (over x)
#pragma unroll
    for (int r = 0; r < 8; ++r) fdct8(X[r]);
#pragma unroll
    for (int v = 0; v < 8; ++v) {
        float t[8];
#pragma unroll
        for (int u = 0; u < 8; ++u) t[u] = X[u][v];
        fdct8(t);
#pragma unroll
        for (int u = 0; u < 8; ++u) X[u][v] = t[u];
    }
    if (ch == 0) quant_block<0>(X); else quant_block<1>(X);
    // inverse: columns, then rows
#pragma unroll
    for (int v = 0; v < 8; ++v) {
        float t[8];
#pragma unroll
        for (int u = 0; u < 8; ++u) t[u] = X[u][v];
        idct8(t);
#pragma unroll
        for (int u = 0; u < 8; ++u) X[u][v] = t[u];
    }
#pragma unroll
    for (int r = 0; r < 8; ++r) idct8(X[r]);
}

__global__ __launch_bounds__(256, 4) void jpeg_kernel(const float* __restrict__ x,
                                                      float* __restrict__ out) {
    // fp16 exchange buffer for reconstructed Y/Cb/Cr: [ch][row][col] = 24 KB
    __shared__ _Float16 ldsH[3 * 8 * 512];

    const int wg = blockIdx.x;
    const int b = wg >> 6;     // batch
    const int gh = wg & 63;    // 8-row strip index
    const int tid = threadIdx.x;

    const float* xb = x + (size_t)b * 3 * IMG_HW + (size_t)gh * 8 * IMG_W;
    float* ob = out + (size_t)b * 3 * IMG_HW + (size_t)gh * 8 * IMG_W;

    // ---------- per-(channel, block) transform; 192 of 256 threads ----------
    if (tid < 192) {
        const int ch = tid >> 6;    // wave index = channel
        const int blk = tid & 63;   // lane = 8x8 block within the strip

        // forward color weights for this thread's channel (wave-uniform)
        float w0, w1, w2, woff;
        if (ch == 0)      { w0 = 0.299f;     w1 = 0.587f;     w2 = 0.114f;     woff = -0.5f; }
        else if (ch == 1) { w0 = -0.168736f; w1 = -0.331264f; w2 = 0.5f;       woff = 0.0f;  }
        else              { w0 = 0.5f;       w1 = -0.418688f; w2 = -0.081312f; woff = 0.0f;  }

        const float* pr = xb + blk * 8;
        const float* pg = pr + IMG_HW;
        const float* pb = pg + IMG_HW;

        float X[8][8];
#pragma unroll
        for (int r = 0; r < 8; ++r) {
            // 32B loads; the 3 waves read the same lines -> L1/L2 hits, HBM once
            f8v rv = *(const f8v*)(pr + r * IMG_W);
            f8v gv = *(const f8v*)(pg + r * IMG_W);
            f8v bv = *(const f8v*)(pb + r * IMG_W);
#pragma unroll
            for (int k = 0; k < 8; ++k)
                X[r][k] = w0 * rv[k] + w1 * gv[k] + w2 * bv[k] + woff;
        }

        transform_block(X, ch);

        // write reconstructed channel block to LDS as fp16 (16B/lane, contiguous)
#pragma unroll
        for (int r = 0; r < 8; ++r) {
            half8 h;
#pragma unroll
            for (int k = 0; k < 8; ++k) h[k] = (_Float16)X[r][k];
            *(half8*)&ldsH[(ch * 8 + r) * 512 + blk * 8] = h;
        }
    }
    __syncthreads();

    // ---------- inverse color + store (all 256 threads) ----------
#pragma unroll
    for (int i = 0; i < 2; ++i) {
        int g = i * 256 + tid;        // 0..511 groups of 8 px
        int r = g >> 6;               // 0..7
        int col8 = (g & 63) << 3;     // 0..504
        half8 hy  = *(half8*)&ldsH[(0 * 8 + r) * 512 + col8];
        half8 hcb = *(half8*)&ldsH[(1 * 8 + r) * 512 + col8];
        half8 hcr = *(half8*)&ldsH[(2 * 8 + r) * 512 + col8];
        f8v R, G, B;
#pragma unroll
        for (int k = 0; k < 8; ++k) {
            float Y  = (float)hy[k] + 0.5f;
            float Cb = (float)hcb[k];
            float Cr = (float)hcr[k];
            float Rv = Y + 1.402f * Cr;
            float Gv = Y - 0.344136f * Cb - 0.714136f * Cr;
            float Bv = Y + 1.772f * Cb;
            R[k] = fminf(fmaxf(Rv, 0.0f), 1.0f);
            G[k] = fminf(fmaxf(Gv, 0.0f), 1.0f);
            B[k] = fminf(fmaxf(Bv, 0.0f), 1.0f);
        }
        float* o0 = ob + r * IMG_W + col8;
        *(f8v*)(o0) = R;
        *(f8v*)(o0 + IMG_HW) = G;
        *(f8v*)(o0 + 2 * IMG_HW) = B;
    }
}

extern "C" void kernel_launch(void* const* d_in, const int* in_sizes, int n_in,
                              void* d_out, int out_size, void* d_ws, size_t ws_size,
                              hipStream_t stream) {
    const float* x = (const float*)d_in[0];
    float* out = (float*)d_out;
    const int B = in_sizes[0] / (3 * IMG_HW);   // 32
    const int n_wg = B * 64;                    // one WG per (batch, 8-row strip)
    hipLaunchKernelGGL(jpeg_kernel, dim3(n_wg), dim3(256), 0, stream, x, out);
}

// Round 3
// 67.074 us; speedup vs baseline: 2.6347x; 2.6347x over previous
//
#include <hip/hip_runtime.h>
#include <math.h>

// ---- DCT constants (fp32) ----
#define A0c 0.35355339059327373f
#define C1c 0.4903926402016152f
#define C2c 0.46193976625564337f
#define C3c 0.41573480615127262f
#define C5c 0.27778511650980114f
#define C6c 0.19134171618254492f
#define C7c 0.09754516100806417f

#define IMG_W 512
#define IMG_HW (512 * 512)
#define N_STRIPS_TOTAL (32 * 64)   // batch * strips-per-image

typedef _Float16 half4v __attribute__((ext_vector_type(4)));
typedef _Float16 half8v __attribute__((ext_vector_type(8)));
typedef float f8v __attribute__((ext_vector_type(8)));

// In-place 8-point DCT-II (rows of D = 0.5*c(u)*cos((2x+1)u*pi/16))
__device__ __forceinline__ void fdct8(float v[8]) {
    float s0 = v[0] + v[7], s1 = v[1] + v[6], s2 = v[2] + v[5], s3 = v[3] + v[4];
    float d0 = v[0] - v[7], d1 = v[1] - v[6], d2 = v[2] - v[5], d3 = v[3] - v[4];
    float e0 = s0 + s3, e1 = s1 + s2, f0 = s0 - s3, f1 = s1 - s2;
    v[0] = A0c * (e0 + e1);
    v[4] = A0c * (e0 - e1);
    v[2] = C2c * f0 + C6c * f1;
    v[6] = C6c * f0 - C2c * f1;
    v[1] = C1c * d0 + C3c * d1 + C5c * d2 + C7c * d3;
    v[3] = C3c * d0 - C7c * d1 - C1c * d2 - C5c * d3;
    v[5] = C5c * d0 - C1c * d1 + C7c * d2 + C3c * d3;
    v[7] = C7c * d0 - C5c * d1 + C3c * d2 - C1c * d3;
}

// In-place 8-point inverse: x[n] = sum_u D[u][n] c[u]
__device__ __forceinline__ void idct8(float v[8]) {
    float g0 = v[0], g1 = v[1], g2 = v[2], g3 = v[3];
    float g4 = v[4], g5 = v[5], g6 = v[6], g7 = v[7];
    float ep = A0c * (g0 + g4), em = A0c * (g0 - g4);
    float t26a = C2c * g2 + C6c * g6;
    float t26b = C6c * g2 - C2c * g6;
    float e0 = ep + t26a;
    float e1 = em + t26b;
    float e2 = em - t26b;
    float e3 = ep - t26a;
    float o0 = C1c * g1 + C3c * g3 + C5c * g5 + C7c * g7;
    float o1 = C3c * g1 - C7c * g3 - C1c * g5 - C5c * g7;
    float o2 = C5c * g1 - C1c * g3 + C7c * g5 + C3c * g7;
    float o3 = C7c * g1 - C5c * g3 + C3c * g5 - C1c * g7;
    v[0] = e0 + o0; v[7] = e0 - o0;
    v[1] = e1 + o1; v[6] = e1 - o1;
    v[2] = e2 + o2; v[5] = e2 - o2;
    v[3] = e3 + o3; v[4] = e3 - o3;
}

// soft quantize-dequantize: d = x/q; sr = d + 0.5*tanh(15*(d - round(d))); return sr*q
__device__ __forceinline__ float softq(float x, float q, float rq) {
    float d = x * rq;
    float rn = rintf(d);             // nearest-even, matches jnp.round
    float t = d - rn;                // in [-0.5, 0.5]
    float e = __expf(-30.0f * fabsf(t));   // tanh(15t) via exp, 15*2=30
    float th = (1.0f - e) * __builtin_amdgcn_rcpf(1.0f + e);
    th = copysignf(th, t);
    return (d + 0.5f * th) * q;
}

template <int CH>
__device__ __forceinline__ void quant_block(float X[8][8]) {
    static constexpr float QL[64] = {
        16,11,10,16,24,40,51,61,  12,12,14,19,26,58,60,55,
        14,13,16,24,40,57,69,56,  14,17,22,29,51,87,80,62,
        18,22,37,56,68,109,103,77, 24,35,55,64,81,104,113,92,
        49,64,78,87,103,121,120,101, 72,92,95,98,112,100,103,99};
    static constexpr float QC[64] = {
        17,18,24,47,99,99,99,99,  18,21,26,66,99,99,99,99,
        24,26,56,99,99,99,99,99,  47,66,99,99,99,99,99,99,
        99,99,99,99,99,99,99,99,  99,99,99,99,99,99,99,99,
        99,99,99,99,99,99,99,99,  99,99,99,99,99,99,99,99};
#pragma unroll
    for (int u = 0; u < 8; ++u) {
#pragma unroll
        for (int v = 0; v < 8; ++v) {
            float q = (CH == 0) ? QL[u * 8 + v] : QC[u * 8 + v];
            float rq = (CH == 0) ? (1.0f / QL[u * 8 + v]) : (1.0f / QC[u * 8 + v]);
            X[u][v] = softq(X[u][v], q, rq);
        }
    }
}

__device__ __forceinline__ void transform_block(float X[8][8], int ch) {
    // forward: rows (over y), then columns (over x)
#pragma unroll
    for (int r = 0; r < 8; ++r) fdct8(X[r]);
#pragma unroll
    for (int v = 0; v < 8; ++v) {
        float t[8];
#pragma unroll
        for (int u = 0; u < 8; ++u) t[u] = X[u][v];
        fdct8(t);
#pragma unroll
        for (int u = 0; u < 8; ++u) X[u][v] = t[u];
    }
    if (ch == 0) quant_block<0>(X); else quant_block<1>(X);
    // inverse: columns, then rows
#pragma unroll
    for (int v = 0; v < 8; ++v) {
        float t[8];
#pragma unroll
        for (int u = 0; u < 8; ++u) t[u] = X[u][v];
        idct8(t);
#pragma unroll
        for (int u = 0; u < 8; ++u) X[u][v] = t[u];
    }
#pragma unroll
    for (int r = 0; r < 8; ++r) idct8(X[r]);
}

__global__ __launch_bounds__(256) void jpeg_kernel(const float* __restrict__ x,
                                                   float* __restrict__ out) {
    // fp16 staging/exchange for Y/Cb/Cr: [ch][row][col], 3*8*512*2B = 24 KB.
    // Used in-place: phase A writes forward-transformed color, phase B
    // overwrites each 8x8 block with its reconstruction, phase C reads it.
    __shared__ _Float16 ldsH[3 * 8 * 512];

    const int tid = threadIdx.x;

    for (int s = blockIdx.x; s < N_STRIPS_TOTAL; s += gridDim.x) {
        const int b = s >> 6;     // batch
        const int gh = s & 63;    // 8-row strip index

        const float* xb = x + (size_t)b * 3 * IMG_HW + (size_t)gh * 8 * IMG_W;
        float* ob = out + (size_t)b * 3 * IMG_HW + (size_t)gh * 8 * IMG_W;

        // ---------- phase A: coalesced load + forward color -> fp16 LDS ----------
#pragma unroll
        for (int i = 0; i < 4; ++i) {
            int n4 = i * 256 + tid;          // 0..1023 float4-slots of 8x512 strip
            int r = n4 >> 7;                 // 0..7
            int col4 = (n4 & 127) << 2;      // 0..508
            const float4 rv = *(const float4*)(xb + 0 * IMG_HW + r * IMG_W + col4);
            const float4 gv = *(const float4*)(xb + 1 * IMG_HW + r * IMG_W + col4);
            const float4 bv = *(const float4*)(xb + 2 * IMG_HW + r * IMG_W + col4);
            half4v yv, cbv, crv;
            const float* rp = &rv.x; const float* gp = &gv.x; const float* bp = &bv.x;
#pragma unroll
            for (int k = 0; k < 4; ++k) {
                float R = rp[k], G = gp[k], B = bp[k];
                yv[k]  = (_Float16)(0.299f * R + 0.587f * G + 0.114f * B - 0.5f);
                cbv[k] = (_Float16)(-0.168736f * R - 0.331264f * G + 0.5f * B);
                crv[k] = (_Float16)(0.5f * R - 0.418688f * G - 0.081312f * B);
            }
            *(half4v*)&ldsH[0 * 4096 + r * 512 + col4] = yv;
            *(half4v*)&ldsH[1 * 4096 + r * 512 + col4] = cbv;
            *(half4v*)&ldsH[2 * 4096 + r * 512 + col4] = crv;
        }
        __syncthreads();

        // ---------- phase B: per-(channel, block) transform; 192 of 256 threads ----------
        if (tid < 192) {
            const int ch = tid >> 6;    // wave index = channel
            const int blk = tid & 63;   // lane = 8x8 block within the strip
            float X[8][8];
#pragma unroll
            for (int r = 0; r < 8; ++r) {
                half8v h = *(half8v*)&ldsH[ch * 4096 + r * 512 + blk * 8];
#pragma unroll
                for (int k = 0; k < 8; ++k) X[r][k] = (float)h[k];
            }
            transform_block(X, ch);
#pragma unroll
            for (int r = 0; r < 8; ++r) {
                half8v h;
#pragma unroll
                for (int k = 0; k < 8; ++k) h[k] = (_Float16)X[r][k];
                *(half8v*)&ldsH[ch * 4096 + r * 512 + blk * 8] = h;
            }
        }
        __syncthreads();

        // ---------- phase C: inverse color + coalesced store ----------
#pragma unroll
        for (int i = 0; i < 2; ++i) {
            int g = i * 256 + tid;        // 0..511 groups of 8 px
            int r = g >> 6;               // 0..7
            int col8 = (g & 63) << 3;     // 0..504
            half8v hy  = *(half8v*)&ldsH[0 * 4096 + r * 512 + col8];
            half8v hcb = *(half8v*)&ldsH[1 * 4096 + r * 512 + col8];
            half8v hcr = *(half8v*)&ldsH[2 * 4096 + r * 512 + col8];
            f8v R, G, B;
#pragma unroll
            for (int k = 0; k < 8; ++k) {
                float Y  = (float)hy[k] + 0.5f;
                float Cb = (float)hcb[k];
                float Cr = (float)hcr[k];
                float Rv = Y + 1.402f * Cr;
                float Gv = Y - 0.344136f * Cb - 0.714136f * Cr;
                float Bv = Y + 1.772f * Cb;
                R[k] = fminf(fmaxf(Rv, 0.0f), 1.0f);
                G[k] = fminf(fmaxf(Gv, 0.0f), 1.0f);
                B[k] = fminf(fmaxf(Bv, 0.0f), 1.0f);
            }
            float* o0 = ob + r * IMG_W + col8;
            *(f8v*)(o0) = R;
            *(f8v*)(o0 + IMG_HW) = G;
            *(f8v*)(o0 + 2 * IMG_HW) = B;
        }
        __syncthreads();   // protect LDS reuse across grid-stride iterations
    }
}

extern "C" void kernel_launch(void* const* d_in, const int* in_sizes, int n_in,
                              void* d_out, int out_size, void* d_ws, size_t ws_size,
                              hipStream_t stream) {
    const float* x = (const float*)d_in[0];
    float* out = (float*)d_out;
    // 1024 WGs, each handles 2 strips: ~4 blocks/CU concurrent = 1 residency
    // round, minimizing ramp/tail vs launching 2048 one-shot WGs.
    const int n_wg = 1024;
    hipLaunchKernelGGL(jpeg_kernel, dim3(n_wg), dim3(256), 0, stream, x, out);
}

// Round 4
// 59.151 us; speedup vs baseline: 2.9876x; 1.1339x over previous
//
#include <hip/hip_runtime.h>
#include <math.h>

// ---- DCT constants (fp32) ----
#define A0c 0.35355339059327373f
#define C1c 0.4903926402016152f
#define C2c 0.46193976625564337f
#define C3c 0.41573480615127262f
#define C5c 0.27778511650980114f
#define C6c 0.19134171618254492f
#define C7c 0.09754516100806417f

#define IMG_W 512
#define IMG_HW (512 * 512)

typedef _Float16 half4v __attribute__((ext_vector_type(4)));
typedef _Float16 half8v __attribute__((ext_vector_type(8)));
typedef float f8v __attribute__((ext_vector_type(8)));

// In-place 8-point DCT-II (rows of D = 0.5*c(u)*cos((2x+1)u*pi/16))
__device__ __forceinline__ void fdct8(float v[8]) {
    float s0 = v[0] + v[7], s1 = v[1] + v[6], s2 = v[2] + v[5], s3 = v[3] + v[4];
    float d0 = v[0] - v[7], d1 = v[1] - v[6], d2 = v[2] - v[5], d3 = v[3] - v[4];
    float e0 = s0 + s3, e1 = s1 + s2, f0 = s0 - s3, f1 = s1 - s2;
    v[0] = A0c * (e0 + e1);
    v[4] = A0c * (e0 - e1);
    v[2] = C2c * f0 + C6c * f1;
    v[6] = C6c * f0 - C2c * f1;
    v[1] = C1c * d0 + C3c * d1 + C5c * d2 + C7c * d3;
    v[3] = C3c * d0 - C7c * d1 - C1c * d2 - C5c * d3;
    v[5] = C5c * d0 - C1c * d1 + C7c * d2 + C3c * d3;
    v[7] = C7c * d0 - C5c * d1 + C3c * d2 - C1c * d3;
}

// In-place 8-point inverse: x[n] = sum_u D[u][n] c[u]
__device__ __forceinline__ void idct8(float v[8]) {
    float g0 = v[0], g1 = v[1], g2 = v[2], g3 = v[3];
    float g4 = v[4], g5 = v[5], g6 = v[6], g7 = v[7];
    float ep = A0c * (g0 + g4), em = A0c * (g0 - g4);
    float t26a = C2c * g2 + C6c * g6;
    float t26b = C6c * g2 - C2c * g6;
    float e0 = ep + t26a;
    float e1 = em + t26b;
    float e2 = em - t26b;
    float e3 = ep - t26a;
    float o0 = C1c * g1 + C3c * g3 + C5c * g5 + C7c * g7;
    float o1 = C3c * g1 - C7c * g3 - C1c * g5 - C5c * g7;
    float o2 = C5c * g1 - C1c * g3 + C7c * g5 + C3c * g7;
    float o3 = C7c * g1 - C5c * g3 + C3c * g5 - C1c * g7;
    v[0] = e0 + o0; v[7] = e0 - o0;
    v[1] = e1 + o1; v[6] = e1 - o1;
    v[2] = e2 + o2; v[5] = e2 - o2;
    v[3] = e3 + o3; v[4] = e3 - o3;
}

// soft quantize-dequantize: d = x/q; sr = d + 0.5*tanh(15*(d - round(d))); return sr*q
__device__ __forceinline__ float softq(float x, float q, float rq) {
    float d = x * rq;
    float rn = rintf(d);                   // nearest-even, matches jnp.round
    float t = d - rn;                      // in [-0.5, 0.5]
    float e = __expf(-30.0f * fabsf(t));   // tanh(15t) via exp
    float th = (1.0f - e) * __builtin_amdgcn_rcpf(1.0f + e);
    th = copysignf(th, t);
    return (d + 0.5f * th) * q;
}

template <int CH>
__device__ __forceinline__ void quant_block(float X[8][8]) {
    static constexpr float QL[64] = {
        16,11,10,16,24,40,51,61,  12,12,14,19,26,58,60,55,
        14,13,16,24,40,57,69,56,  14,17,22,29,51,87,80,62,
        18,22,37,56,68,109,103,77, 24,35,55,64,81,104,113,92,
        49,64,78,87,103,121,120,101, 72,92,95,98,112,100,103,99};
    static constexpr float QC[64] = {
        17,18,24,47,99,99,99,99,  18,21,26,66,99,99,99,99,
        24,26,56,99,99,99,99,99,  47,66,99,99,99,99,99,99,
        99,99,99,99,99,99,99,99,  99,99,99,99,99,99,99,99,
        99,99,99,99,99,99,99,99,  99,99,99,99,99,99,99,99};
#pragma unroll
    for (int u = 0; u < 8; ++u) {
#pragma unroll
        for (int v = 0; v < 8; ++v) {
            float q = (CH == 0) ? QL[u * 8 + v] : QC[u * 8 + v];
            float rq = (CH == 0) ? (1.0f / QL[u * 8 + v]) : (1.0f / QC[u * 8 + v]);
            X[u][v] = softq(X[u][v], q, rq);
        }
    }
}

// Block = 192 threads = 3 waves, one wave per channel in phase B (no idle
// lanes). No min-waves launch bound (R2 lesson: forcing it spills). 24 KB LDS
// -> residency limited by VGPRs: <=128 gives 5 WG/CU = 15 waves/CU.
__global__ __launch_bounds__(192) void jpeg_kernel(const float* __restrict__ x,
                                                   float* __restrict__ out) {
    // fp16 staging/exchange for Y/Cb/Cr: [ch][row][col], 3*8*512*2B = 24 KB.
    // In-place: phase A writes forward color, phase B overwrites each 8x8
    // block with its reconstruction, phase C reads it back.
    __shared__ _Float16 ldsH[3 * 8 * 512];

    const int tid = threadIdx.x;
    const int s = blockIdx.x;
    const int b = s >> 6;     // batch
    const int gh = s & 63;    // 8-row strip index

    const float* xb = x + (size_t)b * 3 * IMG_HW + (size_t)gh * 8 * IMG_W;
    float* ob = out + (size_t)b * 3 * IMG_HW + (size_t)gh * 8 * IMG_W;

    // ---------- phase A: coalesced load + forward color -> fp16 LDS ----------
#pragma unroll
    for (int i = 0; i < 6; ++i) {
        int n4 = i * 192 + tid;          // 0..1151; 1024 float4-slots of 8x512
        if (n4 < 1024) {
            int r = n4 >> 7;                 // 0..7
            int col4 = (n4 & 127) << 2;      // 0..508
            const float4 rv = *(const float4*)(xb + 0 * IMG_HW + r * IMG_W + col4);
            const float4 gv = *(const float4*)(xb + 1 * IMG_HW + r * IMG_W + col4);
            const float4 bv = *(const float4*)(xb + 2 * IMG_HW + r * IMG_W + col4);
            half4v yv, cbv, crv;
            const float* rp = &rv.x; const float* gp = &gv.x; const float* bp = &bv.x;
#pragma unroll
            for (int k = 0; k < 4; ++k) {
                float R = rp[k], G = gp[k], B = bp[k];
                yv[k]  = (_Float16)(0.299f * R + 0.587f * G + 0.114f * B - 0.5f);
                cbv[k] = (_Float16)(-0.168736f * R - 0.331264f * G + 0.5f * B);
                crv[k] = (_Float16)(0.5f * R - 0.418688f * G - 0.081312f * B);
            }
            *(half4v*)&ldsH[0 * 4096 + r * 512 + col4] = yv;
            *(half4v*)&ldsH[1 * 4096 + r * 512 + col4] = cbv;
            *(half4v*)&ldsH[2 * 4096 + r * 512 + col4] = crv;
        }
    }
    __syncthreads();

    // ---------- phase B: per-(channel, block) transform; all 192 threads ----------
    {
        const int ch = tid >> 6;    // wave index = channel
        const int blk = tid & 63;   // lane = 8x8 block within the strip
        float X[8][8];
#pragma unroll
        for (int r = 0; r < 8; ++r) {
            half8v h = *(half8v*)&ldsH[ch * 4096 + r * 512 + blk * 8];
#pragma unroll
            for (int k = 0; k < 8; ++k) X[r][k] = (float)h[k];
        }
        // forward: rows, then columns
#pragma unroll
        for (int r = 0; r < 8; ++r) fdct8(X[r]);
#pragma unroll
        for (int v = 0; v < 8; ++v) {
            float t[8];
#pragma unroll
            for (int u = 0; u < 8; ++u) t[u] = X[u][v];
            fdct8(t);
#pragma unroll
            for (int u = 0; u < 8; ++u) X[u][v] = t[u];
        }
        if (ch == 0) quant_block<0>(X); else quant_block<1>(X);
        // inverse: columns, then rows (row idct fused with fp16 convert+store
        // to shorten live ranges)
#pragma unroll
        for (int v = 0; v < 8; ++v) {
            float t[8];
#pragma unroll
            for (int u = 0; u < 8; ++u) t[u] = X[u][v];
            idct8(t);
#pragma unroll
            for (int u = 0; u < 8; ++u) X[u][v] = t[u];
        }
#pragma unroll
        for (int r = 0; r < 8; ++r) {
            idct8(X[r]);
            half8v h;
#pragma unroll
            for (int k = 0; k < 8; ++k) h[k] = (_Float16)X[r][k];
            *(half8v*)&ldsH[ch * 4096 + r * 512 + blk * 8] = h;
        }
    }
    __syncthreads();

    // ---------- phase C: inverse color + coalesced store ----------
#pragma unroll
    for (int i = 0; i < 3; ++i) {
        int g = i * 192 + tid;        // 0..575; 512 groups of 8 px
        if (g < 512) {
            int r = g >> 6;               // 0..7
            int col8 = (g & 63) << 3;     // 0..504
            half8v hy  = *(half8v*)&ldsH[0 * 4096 + r * 512 + col8];
            half8v hcb = *(half8v*)&ldsH[1 * 4096 + r * 512 + col8];
            half8v hcr = *(half8v*)&ldsH[2 * 4096 + r * 512 + col8];
            f8v R, G, B;
#pragma unroll
            for (int k = 0; k < 8; ++k) {
                float Y  = (float)hy[k] + 0.5f;
                float Cb = (float)hcb[k];
                float Cr = (float)hcr[k];
                float Rv = Y + 1.402f * Cr;
                float Gv = Y - 0.344136f * Cb - 0.714136f * Cr;
                float Bv = Y + 1.772f * Cb;
                R[k] = fminf(fmaxf(Rv, 0.0f), 1.0f);
                G[k] = fminf(fmaxf(Gv, 0.0f), 1.0f);
                B[k] = fminf(fmaxf(Bv, 0.0f), 1.0f);
            }
            float* o0 = ob + r * IMG_W + col8;
            *(f8v*)(o0) = R;
            *(f8v*)(o0 + IMG_HW) = G;
            *(f8v*)(o0 + 2 * IMG_HW) = B;
        }
    }
}

extern "C" void kernel_launch(void* const* d_in, const int* in_sizes, int n_in,
                              void* d_out, int out_size, void* d_ws, size_t ws_size,
                              hipStream_t stream) {
    const float* x = (const float*)d_in[0];
    float* out = (float*)d_out;
    const int B = in_sizes[0] / (3 * IMG_HW);   // 32
    const int n_wg = B * 64;                    // one WG per (batch, 8-row strip)
    hipLaunchKernelGGL(jpeg_kernel, dim3(n_wg), dim3(192), 0, stream, x, out);
}